// Round 1
// baseline (8368.098 us; speedup 1.0000x reference)
//
#include <hip/hip_runtime.h>
#include <math.h>

#define NB 512      // batch
#define NT 512      // time
#define NCTRL 256
#define NWORD 128
#define NMEM 128
#define NDIN 64
#define NACT 448    // x(64) | read(128) | ctrl(256)
#define EPSF 1e-6f

// fp16 weight panel, CHUNK-TRANSPOSED layout (identical to round 8):
//   element(region, kc, col, e) at region_base + (kc*NCOLS + col)*8 + e
#define H_WA   0        // rz:    56 kc x 512 cols x 8
#define H_WNI  229376   // inn:   24 kc x 256 cols x 8
#define H_WNH  278528   // hn:    32 kc x 256 cols x 8
#define H_WH   344064   // heads: 32 kc x 512 cols x 8 (key|erase|add|beta|pad)
#define H_TOTAL 475136
#define B_BA   0        // [512] b_ih+b_hh (r,z)
#define B_BNI  512      // [256]
#define B_BNH  768      // [256]
#define B_BH   1024     // [512]
#define B_TOTAL 1536
#define WS_BYTES (H_TOTAL * 2 + B_TOTAL * 4)

typedef _Float16 h2 __attribute__((ext_vector_type(2)));
typedef _Float16 h8 __attribute__((ext_vector_type(8)));
union H8 { h8 v; h2 d[4]; };

__device__ __forceinline__ float sigf(float x) { return 1.0f / (1.0f + expf(-x)); }
__device__ __forceinline__ float softplusf(float x) {
    return (x > 15.0f) ? x : log1pf(expf(x));
}
__device__ __forceinline__ float fdot2(h2 a, h2 b, float c) {
#if __has_builtin(__builtin_amdgcn_fdot2)
    return __builtin_amdgcn_fdot2(a, b, c, false);
#else
    return fmaf((float)a[0], (float)b[0], fmaf((float)a[1], (float)b[1], c));
#endif
}

__global__ __launch_bounds__(256) void prep_kernel(
    const float* __restrict__ Wih, const float* __restrict__ bih,
    const float* __restrict__ Whh, const float* __restrict__ bhh,
    const float* __restrict__ Wkey, const float* __restrict__ bkey,
    const float* __restrict__ Wbeta, const float* __restrict__ bbeta,
    const float* __restrict__ Wer, const float* __restrict__ ber,
    const float* __restrict__ Wadd, const float* __restrict__ badd,
    _Float16* __restrict__ wsH, float* __restrict__ wsB)
{
    int i = blockIdx.x * 256 + threadIdx.x;
    if (i < H_TOTAL) {
        float v;
        if (i < H_WNI) {                       // rz [kc][512][8]
            int ch = i >> 3, e = i & 7;
            int kc = ch >> 9, col = ch & 511;
            int k = kc * 8 + e;
            v = (k < 192) ? Wih[col * 192 + k] : Whh[col * 256 + (k - 192)];
        } else if (i < H_WNH) {                // inn [kc][256][8], k<192
            int i2 = i - H_WNI; int ch = i2 >> 3, e = i2 & 7;
            int kc = ch >> 8, col = ch & 255;
            v = Wih[(512 + col) * 192 + kc * 8 + e];
        } else if (i < H_WH) {                 // hn [kc][256][8], k<256
            int i2 = i - H_WNH; int ch = i2 >> 3, e = i2 & 7;
            int kc = ch >> 8, col = ch & 255;
            v = Whh[(512 + col) * 256 + kc * 8 + e];
        } else {                               // heads [kc][512][8], k<256
            int i2 = i - H_WH; int ch = i2 >> 3, e = i2 & 7;
            int kc = ch >> 9, col = ch & 511;
            int k = kc * 8 + e;
            if (col < 128)       v = Wkey[col * 256 + k];
            else if (col < 256)  v = Wer[(col - 128) * 256 + k];
            else if (col < 384)  v = Wadd[(col - 256) * 256 + k];
            else if (col == 384) v = Wbeta[k];
            else                 v = 0.0f;
        }
        wsH[i] = (_Float16)v;
    } else if (i < H_TOTAL + B_TOTAL) {
        int j = i - H_TOTAL;
        float v;
        if (j < 512)        v = bih[j] + bhh[j];
        else if (j < 768)   v = bih[512 + (j - 512)];
        else if (j < 1024)  v = bhh[512 + (j - 768)];
        else {
            int c = j - 1024;
            if (c < 128)       v = bkey[c];
            else if (c < 256)  v = ber[c - 128];
            else if (c < 384)  v = badd[c - 256];
            else if (c == 384) v = bbeta[0];
            else               v = 0.0f;
        }
        wsB[j] = v;
    }
}

// Memory module v2: same barrier skeleton as the verified round-4 version,
// but read+update fused into one column-oriented M pass, and kk/wb preloaded
// as float4. Reads OLD M for cos+read, then updates M in place.
__device__ __forceinline__ void memory_step(
    int tid, float (*M)[NWORD + 1],
    const float* keyv, const float* ev, const float* av,
    float* cosb, float* wb, float* part, float* readv, float* scal)
{
    if (tid < 64) {                       // ||k||
        float s = keyv[tid] * keyv[tid] + keyv[tid + 64] * keyv[tid + 64];
        #pragma unroll
        for (int o = 32; o >= 1; o >>= 1) s += __shfl_xor(s, o);
        if (tid == 0) scal[0] = 1.0f / (sqrtf(s) + EPSF);
    }
    __syncthreads();
    {                                      // cosine sim: 2 threads / row
        int rr = tid >> 1, hh = tid & 1;
        const float* Mr = &M[rr][hh * 64];
        const float4* kk4 = (const float4*)(keyv + hh * 64);
        float s2 = 0.f, sc = 0.f;
        #pragma unroll
        for (int q = 0; q < 16; ++q) {
            float4 k4 = kk4[q];
            float m0 = Mr[4 * q], m1 = Mr[4 * q + 1], m2 = Mr[4 * q + 2], m3 = Mr[4 * q + 3];
            s2 = fmaf(m0, m0, s2); sc = fmaf(m0, k4.x, sc);
            s2 = fmaf(m1, m1, s2); sc = fmaf(m1, k4.y, sc);
            s2 = fmaf(m2, m2, s2); sc = fmaf(m2, k4.z, sc);
            s2 = fmaf(m3, m3, s2); sc = fmaf(m3, k4.w, sc);
        }
        s2 += __shfl_xor(s2, 1);
        sc += __shfl_xor(sc, 1);
        if (hh == 0) cosb[rr] = sc * scal[0] / (sqrtf(s2) + EPSF);
    }
    __syncthreads();
    if (tid < 64) {                       // softmax over 128 logits
        float beta = scal[1];
        float l0 = beta * cosb[tid], l1 = beta * cosb[tid + 64];
        float mx = fmaxf(l0, l1);
        #pragma unroll
        for (int o = 32; o >= 1; o >>= 1) mx = fmaxf(mx, __shfl_xor(mx, o));
        float e0 = expf(l0 - mx), e1 = expf(l1 - mx);
        float s = e0 + e1;
        #pragma unroll
        for (int o = 32; o >= 1; o >>= 1) s += __shfl_xor(s, o);
        float inv = 1.0f / s;
        wb[tid] = e0 * inv;
        wb[tid + 64] = e1 * inv;
    }
    __syncthreads();
    {   // FUSED read+update: thread (j, rh) walks rows rh*64..rh*64+63 of col j.
        // p += w_r * M_old[r][j];  M[r][j] = M_old - w_r*(e_j*M_old - a_j)
        int j = tid & 127, rh = tid >> 7;
        float ej = ev[j], aj = av[j];
        const float4* wb4 = (const float4*)(wb + rh * 64);
        float p = 0.f;
        #pragma unroll
        for (int q = 0; q < 16; ++q) {
            float4 w4 = wb4[q];
            int r = rh * 64 + 4 * q;
            float m0 = M[r][j], m1 = M[r + 1][j], m2 = M[r + 2][j], m3 = M[r + 3][j];
            p = fmaf(w4.x, m0, p);
            p = fmaf(w4.y, m1, p);
            p = fmaf(w4.z, m2, p);
            p = fmaf(w4.w, m3, p);
            M[r][j]     = fmaf(-w4.x, fmaf(ej, m0, -aj), m0);
            M[r + 1][j] = fmaf(-w4.y, fmaf(ej, m1, -aj), m1);
            M[r + 2][j] = fmaf(-w4.z, fmaf(ej, m2, -aj), m2);
            M[r + 3][j] = fmaf(-w4.w, fmaf(ej, m3, -aj), m3);
        }
        part[rh * 128 + j] = p;
    }
    __syncthreads();
    if (tid < 128) readv[tid] = part[tid] + part[128 + tid];
    // no barrier needed: readv[tid] is produced and consumed by thread tid,
    // and all other LDS reuse is separated by next-iteration barriers.
}

// Round-4 shape EXACTLY (256-thr WG, 1 row, ~73 KB LDS, 2 WG/CU, 512 WGs).
// vs round 8: fp16 acts + v_dot2 (half the GEMV VALU), fused rz+inn+hn
// k-sweep (1/3 the GEMV LDS reads), fused memory_step.
__global__ __launch_bounds__(256) void ntm_fast(
    const float* __restrict__ data, const int* __restrict__ batch_sizes,
    const int* __restrict__ unsort, const float* __restrict__ M0,
    const _Float16* __restrict__ wsH, const float* __restrict__ wsB,
    float* __restrict__ out)
{
    __shared__ float M[NMEM][NWORD + 1];
    __shared__ __align__(16) _Float16 actH[NACT];   // fp16 GEMV inputs
    __shared__ __align__(16) float ctrlB[NCTRL];    // fp32 ctrl master
    __shared__ __align__(16) float readv[NWORD], keyv[NWORD], ev[NWORD], av[NWORD];
    __shared__ __align__(16) float cosb[NMEM], wb[NMEM], part[2 * NWORD], scal[2];
    __shared__ int len_sh;

    const int tid = threadIdx.x;
    const int g = blockIdx.x;
    const int b = unsort[g];

    if (tid == 0) {
        int L = 0;
        for (int t = 0; t < NT; ++t) L += (batch_sizes[t] > b);
        len_sh = L;
    }
    for (int i = tid; i < NMEM * NWORD; i += 256)
        M[i >> 7][i & 127] = M0[i];
    ctrlB[tid] = 0.0f;
    if (tid < NWORD) readv[tid] = 0.0f;
    __syncthreads();
    const int len = len_sh;

    const float bA0 = wsB[B_BA + tid],  bA1 = wsB[B_BA + 256 + tid];
    const float bNi = wsB[B_BNI + tid], bNh = wsB[B_BNH + tid];
    const float bH0 = wsB[B_BH + tid],  bH1 = wsB[B_BH + 256 + tid];

    const h8* __restrict__ pA  = (const h8*)(wsH + H_WA);
    const h8* __restrict__ pI  = (const h8*)(wsH + H_WNI);
    const h8* __restrict__ pH  = (const h8*)(wsH + H_WNH);
    const h8* __restrict__ pHD = (const h8*)(wsH + H_WH);
    const h8* A8 = (const h8*)actH;

    for (int t = 0; t < len; ++t) {
        // ---- stage activations as fp16 (state masters stay fp32)
        if (tid < 64)  actH[tid] = (_Float16)data[((long)t * NB + b) * NDIN + tid];
        if (tid < 128) actH[64 + tid] = (_Float16)readv[tid];
        actH[192 + tid] = (_Float16)ctrlB[tid];
        __syncthreads();

        // ---- fused sweep: rz (cols tid, tid+256) + inn/hn (col tid)
        float a0 = bA0, a1 = bA1, c0 = 0.f, c1 = 0.f;
        float ai = bNi, ci = 0.f, ah = bNh, ch = 0.f;
        #pragma unroll 4
        for (int kc = 0; kc < 24; ++kc) {            // k in [0,192): rz + inn
            H8 x;  x.v  = A8[kc];
            H8 w0; w0.v = pA[kc * 512 + tid];
            H8 w1; w1.v = pA[kc * 512 + tid + 256];
            H8 wn; wn.v = pI[kc * 256 + tid];
            a0 = fdot2(x.d[0], w0.d[0], a0); c0 = fdot2(x.d[1], w0.d[1], c0);
            a0 = fdot2(x.d[2], w0.d[2], a0); c0 = fdot2(x.d[3], w0.d[3], c0);
            a1 = fdot2(x.d[0], w1.d[0], a1); c1 = fdot2(x.d[1], w1.d[1], c1);
            a1 = fdot2(x.d[2], w1.d[2], a1); c1 = fdot2(x.d[3], w1.d[3], c1);
            ai = fdot2(x.d[0], wn.d[0], ai); ci = fdot2(x.d[1], wn.d[1], ci);
            ai = fdot2(x.d[2], wn.d[2], ai); ci = fdot2(x.d[3], wn.d[3], ci);
        }
        #pragma unroll 4
        for (int kc = 24; kc < 56; ++kc) {           // k in [192,448): rz + hn
            H8 x;  x.v  = A8[kc];
            H8 w0; w0.v = pA[kc * 512 + tid];
            H8 w1; w1.v = pA[kc * 512 + tid + 256];
            H8 wn; wn.v = pH[(kc - 24) * 256 + tid];
            a0 = fdot2(x.d[0], w0.d[0], a0); c0 = fdot2(x.d[1], w0.d[1], c0);
            a0 = fdot2(x.d[2], w0.d[2], a0); c0 = fdot2(x.d[3], w0.d[3], c0);
            a1 = fdot2(x.d[0], w1.d[0], a1); c1 = fdot2(x.d[1], w1.d[1], c1);
            a1 = fdot2(x.d[2], w1.d[2], a1); c1 = fdot2(x.d[3], w1.d[3], c1);
            ah = fdot2(x.d[0], wn.d[0], ah); ch = fdot2(x.d[1], wn.d[1], ch);
            ah = fdot2(x.d[2], wn.d[2], ah); ch = fdot2(x.d[3], wn.d[3], ch);
        }
        a0 += c0; a1 += c1; ai += ci; ah += ch;

        float rg = sigf(a0), zg = sigf(a1);
        float ng = tanhf(fmaf(rg, ah, ai));
        float cold = ctrlB[tid];            // fp32 master (own element)
        float cnew = fmaf(zg, cold - ng, ng);
        __syncthreads();                    // all GEMV reads of actH done
        ctrlB[tid] = cnew;
        actH[192 + tid] = (_Float16)cnew;
        __syncthreads();

        // ---- heads: cols (tid, tid+256), 32 chunks over new ctrl
        float h0 = bH0, h1 = bH1, d0 = 0.f, d1 = 0.f;
        #pragma unroll 4
        for (int kc = 0; kc < 32; ++kc) {
            H8 x;  x.v  = A8[24 + kc];
            H8 w0; w0.v = pHD[kc * 512 + tid];
            H8 w1; w1.v = pHD[kc * 512 + tid + 256];
            h0 = fdot2(x.d[0], w0.d[0], h0); d0 = fdot2(x.d[1], w0.d[1], d0);
            h0 = fdot2(x.d[2], w0.d[2], h0); d0 = fdot2(x.d[3], w0.d[3], d0);
            h1 = fdot2(x.d[0], w1.d[0], h1); d1 = fdot2(x.d[1], w1.d[1], d1);
            h1 = fdot2(x.d[2], w1.d[2], h1); d1 = fdot2(x.d[3], w1.d[3], d1);
        }
        h0 += d0; h1 += d1;

        if (tid < 128) { keyv[tid] = tanhf(h0); av[tid] = h1; }
        else           { ev[tid - 128] = sigf(h0); }
        if (tid == 128) scal[1] = softplusf(h1);   // col 384 = beta
        __syncthreads();

        memory_step(tid, M, keyv, ev, av, cosb, wb, part, readv, scal);
    }

    out[g * NCTRL + tid] = ctrlB[tid];
    if (tid < NWORD) out[NB * NCTRL + g * NWORD + tid] = readv[tid];
}

// FALLBACK (ws too small): round-4 verified slow path (own memory code).
__global__ __launch_bounds__(256) void ntm_slow(
    const float* __restrict__ data, const int* __restrict__ batch_sizes,
    const int* __restrict__ unsort,
    const float* __restrict__ Wih, const float* __restrict__ bih,
    const float* __restrict__ Whh, const float* __restrict__ bhh,
    const float* __restrict__ Wkey, const float* __restrict__ bkey,
    const float* __restrict__ Wbeta, const float* __restrict__ bbeta,
    const float* __restrict__ Wer, const float* __restrict__ ber,
    const float* __restrict__ Wadd, const float* __restrict__ badd,
    const float* __restrict__ M0, float* __restrict__ out)
{
    __shared__ float M[NMEM][NWORD + 1];
    __shared__ float act[NACT];
    __shared__ float ctrlB[NCTRL];
    __shared__ float gpre[512], ginn[256], ghn[256], hpre[448];
    __shared__ __align__(16) float readv[NWORD], keyv[NWORD], ev[NWORD], av[NWORD];
    __shared__ __align__(16) float cosb[NMEM], wb[NMEM], part[2 * NWORD], scal[2];
    __shared__ int len_sh;

    const int tid = threadIdx.x;
    const int g = blockIdx.x;
    const int b = unsort[g];

    if (tid == 0) {
        int L = 0;
        for (int t = 0; t < NT; ++t) L += (batch_sizes[t] > b);
        len_sh = L;
    }
    for (int i = tid; i < NMEM * NWORD; i += 256)
        M[i >> 7][i & 127] = M0[i];
    ctrlB[tid] = 0.0f;
    if (tid < NWORD) readv[tid] = 0.0f;
    __syncthreads();
    const int len = len_sh;
    const int wave = tid >> 6, lane = tid & 63;

    for (int t = 0; t < len; ++t) {
        if (tid < 64)  act[tid] = data[((long)t * NB + b) * NDIN + tid];
        if (tid < 128) act[64 + tid] = readv[tid];
        act[192 + tid] = ctrlB[tid];
        __syncthreads();

        for (int j = wave; j < 512; j += 4) {
            float p = 0.f;
            for (int k = lane; k < 192; k += 64) p = fmaf(act[k], Wih[j * 192 + k], p);
            for (int k = lane; k < 256; k += 64) p = fmaf(act[192 + k], Whh[j * 256 + k], p);
            #pragma unroll
            for (int o = 32; o >= 1; o >>= 1) p += __shfl_xor(p, o);
            if (lane == 0) gpre[j] = p;
        }
        for (int j = wave; j < 256; j += 4) {
            float pi = 0.f, ph = 0.f;
            for (int k = lane; k < 192; k += 64) pi = fmaf(act[k], Wih[(512 + j) * 192 + k], pi);
            for (int k = lane; k < 256; k += 64) ph = fmaf(act[192 + k], Whh[(512 + j) * 256 + k], ph);
            #pragma unroll
            for (int o = 32; o >= 1; o >>= 1) { pi += __shfl_xor(pi, o); ph += __shfl_xor(ph, o); }
            if (lane == 0) { ginn[j] = pi; ghn[j] = ph; }
        }
        __syncthreads();
        {
            float r = sigf(gpre[tid] + bih[tid] + bhh[tid]);
            float z = sigf(gpre[256 + tid] + bih[256 + tid] + bhh[256 + tid]);
            float inn = ginn[tid] + bih[512 + tid];
            float hn  = ghn[tid] + bhh[512 + tid];
            float n = tanhf(fmaf(r, hn, inn));
            float cold = act[192 + tid];
            ctrlB[tid] = fmaf(z, cold - n, n);
        }
        __syncthreads();
        for (int j = wave; j < 385; j += 4) {
            const float* Wp; long base;
            if (j < 128)      { Wp = Wkey;  base = (long)j * 256; }
            else if (j < 256) { Wp = Wer;   base = (long)(j - 128) * 256; }
            else if (j < 384) { Wp = Wadd;  base = (long)(j - 256) * 256; }
            else              { Wp = Wbeta; base = 0; }
            float p = 0.f;
            for (int k = lane; k < 256; k += 64) p = fmaf(ctrlB[k], Wp[base + k], p);
            #pragma unroll
            for (int o = 32; o >= 1; o >>= 1) p += __shfl_xor(p, o);
            if (lane == 0) hpre[j] = p;
        }
        __syncthreads();
        if (tid < 128) {
            keyv[tid] = tanhf(hpre[tid] + bkey[tid]);
            ev[tid]   = sigf(hpre[128 + tid] + ber[tid]);
            av[tid]   = hpre[256 + tid] + badd[tid];
        }
        if (tid == 0) scal[1] = softplusf(hpre[384] + bbeta[0]);
        __syncthreads();

        memory_step(tid, M, keyv, ev, av, cosb, wb, part, readv, scal);
        __syncthreads();
    }

    out[g * NCTRL + tid] = ctrlB[tid];
    if (tid < NWORD) out[NB * NCTRL + g * NWORD + tid] = readv[tid];
}

extern "C" void kernel_launch(void* const* d_in, const int* in_sizes, int n_in,
                              void* d_out, int out_size, void* d_ws, size_t ws_size,
                              hipStream_t stream)
{
    const float* data       = (const float*)d_in[0];
    const int*  batch_sizes = (const int*)d_in[1];
    const int*  unsort      = (const int*)d_in[2];
    float* out = (float*)d_out;

    if (ws_size >= (size_t)WS_BYTES) {
        _Float16* wsH = (_Float16*)d_ws;
        float* wsB = (float*)((char*)d_ws + (size_t)H_TOTAL * 2);
        prep_kernel<<<(H_TOTAL + B_TOTAL + 255) / 256, 256, 0, stream>>>(
            (const float*)d_in[3], (const float*)d_in[4], (const float*)d_in[5],
            (const float*)d_in[6], (const float*)d_in[7], (const float*)d_in[8],
            (const float*)d_in[9], (const float*)d_in[10], (const float*)d_in[11],
            (const float*)d_in[12], (const float*)d_in[13], (const float*)d_in[14],
            wsH, wsB);
        ntm_fast<<<NB, 256, 0, stream>>>(data, batch_sizes, unsort,
                                         (const float*)d_in[15], wsH, wsB, out);
    } else {
        ntm_slow<<<NB, 256, 0, stream>>>(
            data, batch_sizes, unsort,
            (const float*)d_in[3], (const float*)d_in[4], (const float*)d_in[5],
            (const float*)d_in[6], (const float*)d_in[7], (const float*)d_in[8],
            (const float*)d_in[9], (const float*)d_in[10], (const float*)d_in[11],
            (const float*)d_in[12], (const float*)d_in[13], (const float*)d_in[14],
            (const float*)d_in[15], out);
    }
}

// Round 2
// 6721.491 us; speedup vs baseline: 1.2450x; 1.2450x over previous
//
#include <hip/hip_runtime.h>
#include <math.h>

#define NB 512      // batch
#define NT 512      // time
#define NCTRL 256
#define NWORD 128
#define NMEM 128
#define NDIN 64
#define NACT 448    // x(64) | read(128) | ctrl(256)
#define EPSF 1e-6f

// fp16 weight panel, CHUNK-TRANSPOSED layout (identical to prior rounds):
//   element(region, kc, col, e) at region_base + (kc*NCOLS + col)*8 + e
#define H_WA   0        // rz:    56 kc x 512 cols x 8
#define H_WNI  229376   // inn:   24 kc x 256 cols x 8
#define H_WNH  278528   // hn:    32 kc x 256 cols x 8
#define H_WH   344064   // heads: 32 kc x 512 cols x 8 (key|erase|add|beta|pad)
#define H_TOTAL 475136
#define B_BA   0        // [512] b_ih+b_hh (r,z)
#define B_BNI  512      // [256]
#define B_BNH  768      // [256]
#define B_BH   1024     // [512]
#define B_TOTAL 1536
#define WS_BYTES (H_TOTAL * 2 + B_TOTAL * 4)

typedef _Float16 h2 __attribute__((ext_vector_type(2)));
typedef _Float16 h8 __attribute__((ext_vector_type(8)));
union H8 { h8 v; h2 d[4]; };

__device__ __forceinline__ float sigf(float x) { return 1.0f / (1.0f + expf(-x)); }
__device__ __forceinline__ float softplusf(float x) {
    return (x > 15.0f) ? x : log1pf(expf(x));
}
__device__ __forceinline__ float fdot2(h2 a, h2 b, float c) {
#if __has_builtin(__builtin_amdgcn_fdot2)
    return __builtin_amdgcn_fdot2(a, b, c, false);
#else
    return fmaf((float)a[0], (float)b[0], fmaf((float)a[1], (float)b[1], c));
#endif
}

__global__ __launch_bounds__(256) void prep_kernel(
    const float* __restrict__ Wih, const float* __restrict__ bih,
    const float* __restrict__ Whh, const float* __restrict__ bhh,
    const float* __restrict__ Wkey, const float* __restrict__ bkey,
    const float* __restrict__ Wbeta, const float* __restrict__ bbeta,
    const float* __restrict__ Wer, const float* __restrict__ ber,
    const float* __restrict__ Wadd, const float* __restrict__ badd,
    _Float16* __restrict__ wsH, float* __restrict__ wsB)
{
    int i = blockIdx.x * 256 + threadIdx.x;
    if (i < H_TOTAL) {
        float v;
        if (i < H_WNI) {                       // rz [kc][512][8]
            int ch = i >> 3, e = i & 7;
            int kc = ch >> 9, col = ch & 511;
            int k = kc * 8 + e;
            v = (k < 192) ? Wih[col * 192 + k] : Whh[col * 256 + (k - 192)];
        } else if (i < H_WNH) {                // inn [kc][256][8], k<192
            int i2 = i - H_WNI; int ch = i2 >> 3, e = i2 & 7;
            int kc = ch >> 8, col = ch & 255;
            v = Wih[(512 + col) * 192 + kc * 8 + e];
        } else if (i < H_WH) {                 // hn [kc][256][8], k<256
            int i2 = i - H_WNH; int ch = i2 >> 3, e = i2 & 7;
            int kc = ch >> 8, col = ch & 255;
            v = Whh[(512 + col) * 256 + kc * 8 + e];
        } else {                               // heads [kc][512][8], k<256
            int i2 = i - H_WH; int ch = i2 >> 3, e = i2 & 7;
            int kc = ch >> 9, col = ch & 511;
            int k = kc * 8 + e;
            if (col < 128)       v = Wkey[col * 256 + k];
            else if (col < 256)  v = Wer[(col - 128) * 256 + k];
            else if (col < 384)  v = Wadd[(col - 256) * 256 + k];
            else if (col == 384) v = Wbeta[k];
            else                 v = 0.0f;
        }
        wsH[i] = (_Float16)v;
    } else if (i < H_TOTAL + B_TOTAL) {
        int j = i - H_TOTAL;
        float v;
        if (j < 512)        v = bih[j] + bhh[j];
        else if (j < 768)   v = bih[512 + (j - 512)];
        else if (j < 1024)  v = bhh[512 + (j - 768)];
        else {
            int c = j - 1024;
            if (c < 128)       v = bkey[c];
            else if (c < 256)  v = ber[c - 128];
            else if (c < 384)  v = badd[c - 256];
            else if (c == 384) v = bbeta[0];
            else               v = 0.0f;
        }
        wsB[j] = v;
    }
}

// Memory module: identical math to the verified version, parameterized by
// local thread id u (0..255 within the row's half) and a write-enable flag
// wr (false freezes M/readv for inactive packed rows).
__device__ __forceinline__ void memory_step(
    int u, bool wr, float (*M)[NWORD + 1],
    const float* keyv, const float* ev, const float* av,
    float* cosb, float* wb, float* part, float* readv, float* scal)
{
    if (u < 64) {                       // ||k||
        float s = keyv[u] * keyv[u] + keyv[u + 64] * keyv[u + 64];
        #pragma unroll
        for (int o = 32; o >= 1; o >>= 1) s += __shfl_xor(s, o);
        if (u == 0) scal[0] = 1.0f / (sqrtf(s) + EPSF);
    }
    __syncthreads();
    {                                      // cosine sim: 2 threads / row
        int rr = u >> 1, hh = u & 1;
        const float* Mr = &M[rr][hh * 64];
        const float4* kk4 = (const float4*)(keyv + hh * 64);
        float s2 = 0.f, sc = 0.f;
        #pragma unroll
        for (int p = 0; p < 16; ++p) {
            float4 k4 = kk4[p];
            float m0 = Mr[4 * p], m1 = Mr[4 * p + 1], m2 = Mr[4 * p + 2], m3 = Mr[4 * p + 3];
            s2 = fmaf(m0, m0, s2); sc = fmaf(m0, k4.x, sc);
            s2 = fmaf(m1, m1, s2); sc = fmaf(m1, k4.y, sc);
            s2 = fmaf(m2, m2, s2); sc = fmaf(m2, k4.z, sc);
            s2 = fmaf(m3, m3, s2); sc = fmaf(m3, k4.w, sc);
        }
        s2 += __shfl_xor(s2, 1);
        sc += __shfl_xor(sc, 1);
        if (hh == 0) cosb[rr] = sc * scal[0] / (sqrtf(s2) + EPSF);
    }
    __syncthreads();
    if (u < 64) {                       // softmax over 128 logits
        float beta = scal[1];
        float l0 = beta * cosb[u], l1 = beta * cosb[u + 64];
        float mx = fmaxf(l0, l1);
        #pragma unroll
        for (int o = 32; o >= 1; o >>= 1) mx = fmaxf(mx, __shfl_xor(mx, o));
        float e0 = expf(l0 - mx), e1 = expf(l1 - mx);
        float s = e0 + e1;
        #pragma unroll
        for (int o = 32; o >= 1; o >>= 1) s += __shfl_xor(s, o);
        float inv = 1.0f / s;
        wb[u] = e0 * inv;
        wb[u + 64] = e1 * inv;
    }
    __syncthreads();
    {   // FUSED read+update: thread (j, rh) walks rows rh*64..rh*64+63 of col j.
        int j = u & 127, rh = u >> 7;
        float ej = ev[j], aj = av[j];
        const float4* wb4 = (const float4*)(wb + rh * 64);
        float p = 0.f;
        #pragma unroll
        for (int pq = 0; pq < 16; ++pq) {
            float4 w4 = wb4[pq];
            int r = rh * 64 + 4 * pq;
            float m0 = M[r][j], m1 = M[r + 1][j], m2 = M[r + 2][j], m3 = M[r + 3][j];
            p = fmaf(w4.x, m0, p);
            p = fmaf(w4.y, m1, p);
            p = fmaf(w4.z, m2, p);
            p = fmaf(w4.w, m3, p);
            if (wr) {
                M[r][j]     = fmaf(-w4.x, fmaf(ej, m0, -aj), m0);
                M[r + 1][j] = fmaf(-w4.y, fmaf(ej, m1, -aj), m1);
                M[r + 2][j] = fmaf(-w4.z, fmaf(ej, m2, -aj), m2);
                M[r + 3][j] = fmaf(-w4.w, fmaf(ej, m3, -aj), m3);
            }
        }
        part[rh * 128 + j] = p;
    }
    __syncthreads();
    if (wr && u < 128) readv[u] = part[u] + part[128 + u];
    // no barrier needed: readv[u] is produced and consumed by thread u,
    // and all other LDS reuse is separated by next-iteration barriers.
}

// Two packed rows per 512-thread block: each weight chunk is loaded from L2
// ONCE and dotted against both rows' activations -> L2 weight traffic per
// row-step halves (the measured bottleneck: 29% VALUBusy, 0.04% HBM,
// ~85% of step time = L2 panel delivery). Rows (2g, 2g+1) are adjacent in
// packed (length-sorted) order so lengths nearly match; row1 state writes
// are guarded by wr when ts >= len1. LDS ~152 KB -> 1 WG/CU, 8 waves/CU.
__global__ __launch_bounds__(512) void ntm_fast2(
    const float* __restrict__ data, const int* __restrict__ batch_sizes,
    const int* __restrict__ unsort, const float* __restrict__ M0,
    const _Float16* __restrict__ wsH, const float* __restrict__ wsB,
    float* __restrict__ out)
{
    __shared__ float M[2][NMEM][NWORD + 1];               // 132096 B
    __shared__ __align__(16) _Float16 actH[2][NACT];      // 1792 B
    __shared__ float ctrlB[2][NCTRL];                     // 2048 B
    __shared__ float gA[2][512];                          // 4096 B (rz pre-acts)
    __shared__ float iA[2][NCTRL];                        // 2048 B (inn pre-acts)
    __shared__ float hA[2][NCTRL];                        // 2048 B (hn pre-acts)
    __shared__ __align__(16) float readv[2][NWORD], keyv[2][NWORD], ev[2][NWORD], av[2][NWORD];
    __shared__ __align__(16) float cosb[2][NMEM], wb[2][NMEM], part[2][2 * NWORD], scal[2][2];
    __shared__ int len_sh[2], gpos[2];

    const int t = threadIdx.x;
    const int q = t >> 8;          // row half (0/1)
    const int u = t & 255;         // local tid within half
    const int g = blockIdx.x;
    const int b = 2 * g + q;       // this half's packed row

    if (t < 2) {
        int bb = 2 * g + t;
        int L = 0;
        for (int s = 0; s < NT; ++s) L += (batch_sizes[s] > bb);
        len_sh[t] = L;
    }
    {   // inverse permutation: find out-position of each packed row
        int ug = unsort[t];                 // t in [0,512) == NB
        if (ug == 2 * g)     gpos[0] = t;
        if (ug == 2 * g + 1) gpos[1] = t;
    }
    for (int i = t; i < 2 * NMEM * NWORD; i += 512) {
        int ii = i & (NMEM * NWORD - 1);
        M[i >> 14][ii >> 7][ii & 127] = M0[ii];
    }
    ctrlB[q][u] = 0.0f;
    actH[q][192 + u] = (_Float16)0.0f;
    if (u < NWORD) readv[q][u] = 0.0f;
    __syncthreads();
    const int len0 = len_sh[0], len1 = len_sh[1];   // len0 >= len1 (packed order)

    const float bRZ  = wsB[B_BA + t];
    const float bAux = (t < 256) ? wsB[B_BNI + u] : wsB[B_BNH + u];
    const float bHD  = wsB[B_BH + t];

    const h8* __restrict__ pA  = (const h8*)(wsH + H_WA);
    const h8* __restrict__ pI  = (const h8*)(wsH + H_WNI);
    const h8* __restrict__ pH  = (const h8*)(wsH + H_WNH);
    const h8* __restrict__ pHD = (const h8*)(wsH + H_WH);
    const h8* A0 = (const h8*)actH[0];
    const h8* A1 = (const h8*)actH[1];

    for (int ts = 0; ts < len0; ++ts) {
        const bool wr = (q == 0) | (ts < len1);
        // ---- stage activations as fp16 (same-thread readv staging)
        if (u < 128)      actH[q][64 + u] = (_Float16)readv[q][u];
        else if (u < 192) actH[q][u - 128] =
            (_Float16)data[((long)ts * NB + b) * NDIN + (u - 128)];
        __syncthreads();

        // ---- fused sweep: rz col t (both rows) + aux col u (inn if t<256 else hn)
        float a0 = bRZ, c0 = 0.f, a1 = bRZ, c1 = 0.f;
        float e0 = bAux, f0 = 0.f, e1 = bAux, f1 = 0.f;
        if (t < 256) {
            #pragma unroll 4
            for (int kc = 0; kc < 24; ++kc) {        // k in [0,192): rz + inn
                H8 x0; x0.v = A0[kc];
                H8 x1; x1.v = A1[kc];
                H8 w;  w.v  = pA[kc * 512 + t];
                H8 wn; wn.v = pI[kc * 256 + u];
                a0 = fdot2(x0.d[0], w.d[0], a0);  c0 = fdot2(x0.d[1], w.d[1], c0);
                a0 = fdot2(x0.d[2], w.d[2], a0);  c0 = fdot2(x0.d[3], w.d[3], c0);
                a1 = fdot2(x1.d[0], w.d[0], a1);  c1 = fdot2(x1.d[1], w.d[1], c1);
                a1 = fdot2(x1.d[2], w.d[2], a1);  c1 = fdot2(x1.d[3], w.d[3], c1);
                e0 = fdot2(x0.d[0], wn.d[0], e0); f0 = fdot2(x0.d[1], wn.d[1], f0);
                e0 = fdot2(x0.d[2], wn.d[2], e0); f0 = fdot2(x0.d[3], wn.d[3], f0);
                e1 = fdot2(x1.d[0], wn.d[0], e1); f1 = fdot2(x1.d[1], wn.d[1], f1);
                e1 = fdot2(x1.d[2], wn.d[2], e1); f1 = fdot2(x1.d[3], wn.d[3], f1);
            }
            #pragma unroll 4
            for (int kc = 24; kc < 56; ++kc) {       // k in [192,448): rz only
                H8 x0; x0.v = A0[kc];
                H8 x1; x1.v = A1[kc];
                H8 w;  w.v  = pA[kc * 512 + t];
                a0 = fdot2(x0.d[0], w.d[0], a0);  c0 = fdot2(x0.d[1], w.d[1], c0);
                a0 = fdot2(x0.d[2], w.d[2], a0);  c0 = fdot2(x0.d[3], w.d[3], c0);
                a1 = fdot2(x1.d[0], w.d[0], a1);  c1 = fdot2(x1.d[1], w.d[1], c1);
                a1 = fdot2(x1.d[2], w.d[2], a1);  c1 = fdot2(x1.d[3], w.d[3], c1);
            }
        } else {
            #pragma unroll 4
            for (int kc = 0; kc < 24; ++kc) {        // rz only
                H8 x0; x0.v = A0[kc];
                H8 x1; x1.v = A1[kc];
                H8 w;  w.v  = pA[kc * 512 + t];
                a0 = fdot2(x0.d[0], w.d[0], a0);  c0 = fdot2(x0.d[1], w.d[1], c0);
                a0 = fdot2(x0.d[2], w.d[2], a0);  c0 = fdot2(x0.d[3], w.d[3], c0);
                a1 = fdot2(x1.d[0], w.d[0], a1);  c1 = fdot2(x1.d[1], w.d[1], c1);
                a1 = fdot2(x1.d[2], w.d[2], a1);  c1 = fdot2(x1.d[3], w.d[3], c1);
            }
            #pragma unroll 4
            for (int kc = 24; kc < 56; ++kc) {       // rz + hn
                H8 x0; x0.v = A0[kc];
                H8 x1; x1.v = A1[kc];
                H8 w;  w.v  = pA[kc * 512 + t];
                H8 wn; wn.v = pH[(kc - 24) * 256 + u];
                a0 = fdot2(x0.d[0], w.d[0], a0);  c0 = fdot2(x0.d[1], w.d[1], c0);
                a0 = fdot2(x0.d[2], w.d[2], a0);  c0 = fdot2(x0.d[3], w.d[3], c0);
                a1 = fdot2(x1.d[0], w.d[0], a1);  c1 = fdot2(x1.d[1], w.d[1], c1);
                a1 = fdot2(x1.d[2], w.d[2], a1);  c1 = fdot2(x1.d[3], w.d[3], c1);
                e0 = fdot2(x0.d[0], wn.d[0], e0); f0 = fdot2(x0.d[1], wn.d[1], f0);
                e0 = fdot2(x0.d[2], wn.d[2], e0); f0 = fdot2(x0.d[3], wn.d[3], f0);
                e1 = fdot2(x1.d[0], wn.d[0], e1); f1 = fdot2(x1.d[1], wn.d[1], f1);
                e1 = fdot2(x1.d[2], wn.d[2], e1); f1 = fdot2(x1.d[3], wn.d[3], f1);
            }
        }
        gA[0][t] = a0 + c0;
        gA[1][t] = a1 + c1;
        if (t < 256) { iA[0][u] = e0 + f0; iA[1][u] = e1 + f1; }
        else         { hA[0][u] = e0 + f0; hA[1][u] = e1 + f1; }
        __syncthreads();

        {   // gate combine: thread (q,u) owns ctrl element u of row q
            float rg = sigf(gA[q][u]);
            float zg = sigf(gA[q][NCTRL + u]);
            float ng = tanhf(fmaf(rg, hA[q][u], iA[q][u]));
            float cold = ctrlB[q][u];
            float cnew = fmaf(zg, cold - ng, ng);
            if (wr) {
                ctrlB[q][u] = cnew;
                actH[q][192 + u] = (_Float16)cnew;
            }
        }
        __syncthreads();

        // ---- heads: col t for both rows, 32 chunks over new ctrl
        float h0 = bHD, d0 = 0.f, h1 = bHD, d1 = 0.f;
        #pragma unroll 4
        for (int kc = 0; kc < 32; ++kc) {
            H8 x0; x0.v = A0[24 + kc];
            H8 x1; x1.v = A1[24 + kc];
            H8 w;  w.v  = pHD[kc * 512 + t];
            h0 = fdot2(x0.d[0], w.d[0], h0);  d0 = fdot2(x0.d[1], w.d[1], d0);
            h0 = fdot2(x0.d[2], w.d[2], h0);  d0 = fdot2(x0.d[3], w.d[3], d0);
            h1 = fdot2(x1.d[0], w.d[0], h1);  d1 = fdot2(x1.d[1], w.d[1], d1);
            h1 = fdot2(x1.d[2], w.d[2], h1);  d1 = fdot2(x1.d[3], w.d[3], d1);
        }
        h0 += d0; h1 += d1;
        if (t < 128)       { keyv[0][t] = tanhf(h0);      keyv[1][t] = tanhf(h1); }
        else if (t < 256)  { ev[0][t - 128] = sigf(h0);   ev[1][t - 128] = sigf(h1); }
        else if (t < 384)  { av[0][t - 256] = h0;         av[1][t - 256] = h1; }
        else if (t == 384) { scal[0][1] = softplusf(h0);  scal[1][1] = softplusf(h1); }
        __syncthreads();

        memory_step(u, wr, M[q], keyv[q], ev[q], av[q],
                    cosb[q], wb[q], part[q], readv[q], scal[q]);
    }

    out[gpos[q] * NCTRL + u] = ctrlB[q][u];
    if (u < NWORD) out[NB * NCTRL + gpos[q] * NWORD + u] = readv[q][u];
}

// FALLBACK (ws too small): round-4 verified slow path (own memory code).
__global__ __launch_bounds__(256) void ntm_slow(
    const float* __restrict__ data, const int* __restrict__ batch_sizes,
    const int* __restrict__ unsort,
    const float* __restrict__ Wih, const float* __restrict__ bih,
    const float* __restrict__ Whh, const float* __restrict__ bhh,
    const float* __restrict__ Wkey, const float* __restrict__ bkey,
    const float* __restrict__ Wbeta, const float* __restrict__ bbeta,
    const float* __restrict__ Wer, const float* __restrict__ ber,
    const float* __restrict__ Wadd, const float* __restrict__ badd,
    const float* __restrict__ M0, float* __restrict__ out)
{
    __shared__ float M[NMEM][NWORD + 1];
    __shared__ float act[NACT];
    __shared__ float ctrlB[NCTRL];
    __shared__ float gpre[512], ginn[256], ghn[256], hpre[448];
    __shared__ __align__(16) float readv[NWORD], keyv[NWORD], ev[NWORD], av[NWORD];
    __shared__ __align__(16) float cosb[NMEM], wb[NMEM], part[2 * NWORD], scal[2];
    __shared__ int len_sh;

    const int tid = threadIdx.x;
    const int g = blockIdx.x;
    const int b = unsort[g];

    if (tid == 0) {
        int L = 0;
        for (int t = 0; t < NT; ++t) L += (batch_sizes[t] > b);
        len_sh = L;
    }
    for (int i = tid; i < NMEM * NWORD; i += 256)
        M[i >> 7][i & 127] = M0[i];
    ctrlB[tid] = 0.0f;
    if (tid < NWORD) readv[tid] = 0.0f;
    __syncthreads();
    const int len = len_sh;
    const int wave = tid >> 6, lane = tid & 63;

    for (int t = 0; t < len; ++t) {
        if (tid < 64)  act[tid] = data[((long)t * NB + b) * NDIN + tid];
        if (tid < 128) act[64 + tid] = readv[tid];
        act[192 + tid] = ctrlB[tid];
        __syncthreads();

        for (int j = wave; j < 512; j += 4) {
            float p = 0.f;
            for (int k = lane; k < 192; k += 64) p = fmaf(act[k], Wih[j * 192 + k], p);
            for (int k = lane; k < 256; k += 64) p = fmaf(act[192 + k], Whh[j * 256 + k], p);
            #pragma unroll
            for (int o = 32; o >= 1; o >>= 1) p += __shfl_xor(p, o);
            if (lane == 0) gpre[j] = p;
        }
        for (int j = wave; j < 256; j += 4) {
            float pi = 0.f, ph = 0.f;
            for (int k = lane; k < 192; k += 64) pi = fmaf(act[k], Wih[(512 + j) * 192 + k], pi);
            for (int k = lane; k < 256; k += 64) ph = fmaf(act[192 + k], Whh[(512 + j) * 256 + k], ph);
            #pragma unroll
            for (int o = 32; o >= 1; o >>= 1) { pi += __shfl_xor(pi, o); ph += __shfl_xor(ph, o); }
            if (lane == 0) { ginn[j] = pi; ghn[j] = ph; }
        }
        __syncthreads();
        {
            float r = sigf(gpre[tid] + bih[tid] + bhh[tid]);
            float z = sigf(gpre[256 + tid] + bih[256 + tid] + bhh[256 + tid]);
            float inn = ginn[tid] + bih[512 + tid];
            float hn  = ghn[tid] + bhh[512 + tid];
            float n = tanhf(fmaf(r, hn, inn));
            float cold = act[192 + tid];
            ctrlB[tid] = fmaf(z, cold - n, n);
        }
        __syncthreads();
        for (int j = wave; j < 385; j += 4) {
            const float* Wp; long base;
            if (j < 128)      { Wp = Wkey;  base = (long)j * 256; }
            else if (j < 256) { Wp = Wer;   base = (long)(j - 128) * 256; }
            else if (j < 384) { Wp = Wadd;  base = (long)(j - 256) * 256; }
            else              { Wp = Wbeta; base = 0; }
            float p = 0.f;
            for (int k = lane; k < 256; k += 64) p = fmaf(ctrlB[k], Wp[base + k], p);
            #pragma unroll
            for (int o = 32; o >= 1; o >>= 1) p += __shfl_xor(p, o);
            if (lane == 0) hpre[j] = p;
        }
        __syncthreads();
        if (tid < 128) {
            keyv[tid] = tanhf(hpre[tid] + bkey[tid]);
            ev[tid]   = sigf(hpre[128 + tid] + ber[tid]);
            av[tid]   = hpre[256 + tid] + badd[tid];
        }
        if (tid == 0) scal[1] = softplusf(hpre[384] + bbeta[0]);
        __syncthreads();

        memory_step(tid, true, M, keyv, ev, av, cosb, wb, part, readv, scal);
        __syncthreads();
    }

    out[g * NCTRL + tid] = ctrlB[tid];
    if (tid < NWORD) out[NB * NCTRL + g * NWORD + tid] = readv[tid];
}

extern "C" void kernel_launch(void* const* d_in, const int* in_sizes, int n_in,
                              void* d_out, int out_size, void* d_ws, size_t ws_size,
                              hipStream_t stream)
{
    const float* data       = (const float*)d_in[0];
    const int*  batch_sizes = (const int*)d_in[1];
    const int*  unsort      = (const int*)d_in[2];
    float* out = (float*)d_out;

    if (ws_size >= (size_t)WS_BYTES) {
        _Float16* wsH = (_Float16*)d_ws;
        float* wsB = (float*)((char*)d_ws + (size_t)H_TOTAL * 2);
        prep_kernel<<<(H_TOTAL + B_TOTAL + 255) / 256, 256, 0, stream>>>(
            (const float*)d_in[3], (const float*)d_in[4], (const float*)d_in[5],
            (const float*)d_in[6], (const float*)d_in[7], (const float*)d_in[8],
            (const float*)d_in[9], (const float*)d_in[10], (const float*)d_in[11],
            (const float*)d_in[12], (const float*)d_in[13], (const float*)d_in[14],
            wsH, wsB);
        ntm_fast2<<<NB / 2, 512, 0, stream>>>(data, batch_sizes, unsort,
                                              (const float*)d_in[15], wsH, wsB, out);
    } else {
        ntm_slow<<<NB, 256, 0, stream>>>(
            data, batch_sizes, unsort,
            (const float*)d_in[3], (const float*)d_in[4], (const float*)d_in[5],
            (const float*)d_in[6], (const float*)d_in[7], (const float*)d_in[8],
            (const float*)d_in[9], (const float*)d_in[10], (const float*)d_in[11],
            (const float*)d_in[12], (const float*)d_in[13], (const float*)d_in[14],
            (const float*)d_in[15], out);
    }
}